// Round 14
// baseline (372.029 us; speedup 1.0000x reference)
//
#include <hip/hip_runtime.h>
#include <stdint.h>
#include <stddef.h>

// Problem constants
#define B_    16
#define N_SEQ 4096
#define C_    512
#define H_    8
#define E_    64
#define M_TOT (B_ * N_SEQ)   // 65536
#define QKVN  (3 * C_)       // 1536

typedef __attribute__((ext_vector_type(8))) short short8;
typedef __attribute__((ext_vector_type(4))) short s16x4;
typedef __attribute__((ext_vector_type(4))) float f32x4;

__device__ __forceinline__ unsigned short f2bf(float f) {
  uint32_t u = __builtin_bit_cast(uint32_t, f);
  return (unsigned short)((u + 0x7fffu + ((u >> 16) & 1u)) >> 16);  // RNE
}
__device__ __forceinline__ float bf2f(unsigned short h) {
  uint32_t u = ((uint32_t)h) << 16;
  return __builtin_bit_cast(float, u);
}

// ---------------------------------------------------------------- cvt + zero (one dispatch)
__global__ __launch_bounds__(256) void cvt_all(const float* __restrict__ x,
                                               const float* __restrict__ wq,
                                               const float* __restrict__ wp,
                                               unsigned short* __restrict__ xo,
                                               unsigned short* __restrict__ wqo,
                                               unsigned short* __restrict__ wpo,
                                               float* __restrict__ zbuf) {
  const int bb = blockIdx.x;
  if (bb >= 16896) {
    size_t i = ((size_t)(bb - 16896) * 256 + threadIdx.x) * 4;
    *(float4*)(zbuf + i) = make_float4(0.f, 0.f, 0.f, 0.f);
    return;
  }
  const float* in;
  unsigned short* out;
  size_t base;
  if (bb < 16384)      { in = x;  out = xo;  base = (size_t)bb * 2048; }
  else if (bb < 16768) { in = wq; out = wqo; base = (size_t)(bb - 16384) * 2048; }
  else                 { in = wp; out = wpo; base = (size_t)(bb - 16768) * 2048; }
  size_t i = base + (size_t)threadIdx.x * 8;
  float4 a = *(const float4*)(in + i);
  float4 b = *(const float4*)(in + i + 4);
  short8 o;
  o[0] = (short)f2bf(a.x); o[1] = (short)f2bf(a.y);
  o[2] = (short)f2bf(a.z); o[3] = (short)f2bf(a.w);
  o[4] = (short)f2bf(b.x); o[5] = (short)f2bf(b.y);
  o[6] = (short)f2bf(b.z); o[7] = (short)f2bf(b.w);
  *(short8*)(out + i) = o;
}

#define GLD16(g, l)                                                              \
  __builtin_amdgcn_global_load_lds(                                              \
      (const __attribute__((address_space(1))) void*)(g),                        \
      (__attribute__((address_space(3))) void*)(l), 16, 0, 0)

// ---------------------------------------------------------------- GEMM (C = A * B^T), bf16 in, f32 accum
// OCCUPANCY-FIRST, conflict-free: tile 128x128, 4 waves (wave-tile 64x64,
// acc = 64 AGPR), BK=32, double-buffered LDS = 32 KiB -> 3 blocks/CU
// (96 KiB LDS, ~150 regs/wave = 3 waves/SIMD, __launch_bounds__(256,3)).
// 12 waves/CU: one block's prologue/epilogue overlaps others' K-loops (m114).
// Paired-row XOR swizzle (R10-verified, SQ_LDS_BANK_CONFLICT = 0):
//   row pair p = r>>1 (128B = 8 16B-slots); LDS slot c' = ((r&1)*4+kslot)^(p&7).
//   - staging: LDS position q holds global (p=q>>3, c=(q&7)^(p&7)) ->
//     srcRow = 2p+(c>>2), srcSlot = c&3; coalescing preserved, LDS dest linear.
//   - read (r, kslot=fg): each 8-lane service group covers all 8 bank-quads.
// Schedule per K-tile (R8-proven): STAGE(kt+1) -> swizzled ds_read ->
//   setprio(1) 16 MFMA setprio(0) -> __syncthreads().
// MODE 1: qkv epilogue -> bf16, relu+0.125 on cols < 1024; ksum for k cols
// MODE 2: f32 + bias
template <int MODE>
__global__ __launch_bounds__(256, 3) void gemm_bt(
    const unsigned short* __restrict__ A, const unsigned short* __restrict__ Bm,
    void* __restrict__ Cout, const float* __restrict__ bias,
    float* __restrict__ ksum, int M, int N, int NT) {
  const int K = 512;
  __shared__ unsigned short As[2][128 * 32];   // 16 KiB
  __shared__ unsigned short Bs[2][128 * 32];   // 16 KiB
  // XCD-aware bijective swizzle (grid % 8 == 0)
  const int q8 = gridDim.x >> 3;
  int bid = blockIdx.x;
  bid = (bid & 7) * q8 + (bid >> 3);
  const int mt = bid / NT, nt = bid - mt * NT;
  const int row0 = mt << 7, col0 = nt << 7;
  const int tid = threadIdx.x;
  const int lane = tid & 63, wave = tid >> 6;
  const int wm = wave & 1, wn = wave >> 1;   // wave tile: rows wm*64, cols wn*64
  const int fr = lane & 15, fg = lane >> 4;

  // staging source pointers (inverse paired swizzle); 2 chunks each for A,B
  const unsigned short* sA[2];
  const unsigned short* sB[2];
#pragma unroll
  for (int i = 0; i < 2; i++) {
    const int q = i * 256 + tid, p = q >> 3, c = (q & 7) ^ (p & 7);
    sA[i] = A + (size_t)(row0 + 2 * p + (c >> 2)) * K + (c & 3) * 8;
    sB[i] = Bm + (size_t)(col0 + 2 * p + (c >> 2)) * K + (c & 3) * 8;
  }

  f32x4 acc[4][4] = {};

#define STAGE(kt)                                                  \
  {                                                                \
    unsigned short* dA = &As[(kt) & 1][tid * 8];                   \
    unsigned short* dB = &Bs[(kt) & 1][tid * 8];                   \
    GLD16(sA[0] + (kt) * 32, dA);                                  \
    GLD16(sA[1] + (kt) * 32, dA + 2048);                           \
    GLD16(sB[0] + (kt) * 32, dB);                                  \
    GLD16(sB[1] + (kt) * 32, dB + 2048);                           \
  }

  STAGE(0);
  __syncthreads();   // tile 0 resident

  for (int kt = 0; kt < 16; ++kt) {
    if (kt < 15) STAGE(kt + 1);
    const unsigned short* bufA = As[kt & 1];
    const unsigned short* bufB = Bs[kt & 1];
    short8 af[4], bg[4];
#pragma unroll
    for (int m = 0; m < 4; m++) {
      const int r = wm * 64 + m * 16 + fr, p = r >> 1;
      const int cp = (((r & 1) << 2) | fg) ^ (p & 7);
      af[m] = *(const short8*)&bufA[p * 64 + cp * 8];
    }
#pragma unroll
    for (int n = 0; n < 4; n++) {
      const int r = wn * 64 + n * 16 + fr, p = r >> 1;
      const int cp = (((r & 1) << 2) | fg) ^ (p & 7);
      bg[n] = *(const short8*)&bufB[p * 64 + cp * 8];
    }
    __builtin_amdgcn_s_setprio(1);
#pragma unroll
    for (int m = 0; m < 4; m++)
#pragma unroll
      for (int n = 0; n < 4; n++)
        acc[m][n] = __builtin_amdgcn_mfma_f32_16x16x32_bf16(af[m], bg[n], acc[m][n], 0, 0, 0);
    __builtin_amdgcn_s_setprio(0);
    __syncthreads();   // next tile staged + this tile's readers joined
  }
#undef STAGE

  if (MODE == 1) {
    unsigned short* Cq = (unsigned short*)Cout;
    const int cw0 = col0 + wn * 64;
    const bool isqk = (cw0 < 2 * C_);
    const bool isk = (cw0 >= C_) && (cw0 < 2 * C_);
    float ksp[4] = {0.f, 0.f, 0.f, 0.f};
#pragma unroll
    for (int m = 0; m < 4; m++) {
      const int r0 = row0 + wm * 64 + m * 16 + fg * 4;
#pragma unroll
      for (int n = 0; n < 4; n++) {
        const int c = cw0 + n * 16 + fr;
#pragma unroll
        for (int r = 0; r < 4; r++) {
          float v = acc[m][n][r];
          if (isqk) v = fmaxf(v, 0.0f) + 0.125f;   // relu + E^-0.5
          if (isk) ksp[n] += v;
          Cq[(size_t)(r0 + r) * N + c] = f2bf(v);
        }
      }
    }
    if (isk) {
      const int b = row0 >> 12;
#pragma unroll
      for (int n = 0; n < 4; n++) {
        float s = ksp[n];
        s += __shfl_xor(s, 16, 64);
        s += __shfl_xor(s, 32, 64);
        if (lane < 16) {
          const int cc = cw0 + n * 16 + lane - C_;  // 0..511
          atomicAdd(&ksum[(size_t)((b << 3) + (cc >> 6)) * 64 + (cc & 63)], s);
        }
      }
    }
  } else {
    float* Cf = (float*)Cout;
#pragma unroll
    for (int m = 0; m < 4; m++) {
      const int r0 = row0 + wm * 64 + m * 16 + fg * 4;
#pragma unroll
      for (int n = 0; n < 4; n++) {
        const int c = col0 + wn * 64 + n * 16 + fr;
        const float bb = bias[c];
#pragma unroll
        for (int r = 0; r < 4; r++)
          Cf[(size_t)(r0 + r) * N + c] = acc[m][n][r] + bb;
      }
    }
  }
}

// ---------------------------------------------------------------- KV^T via MFMA (proven)
__global__ __launch_bounds__(256) void kv_mfma(const unsigned short* __restrict__ qkv,
                                               float* __restrict__ KVT) {
  const int bid = blockIdx.x;
  const int ch = bid & 7, bh = bid >> 3;
  const int h = bh & 7, b = bh >> 3;
  const int n0 = ch << 9;
  __shared__ unsigned short ktile[64][68];
  __shared__ unsigned short vtile[64][68];
  const int tid = threadIdx.x;
  const int lane = tid & 63, w = tid >> 6;
  const int fr = lane & 15, fg = lane >> 4;
  const int srow = tid >> 3;
  const int sseg = (tid & 7) << 3;
  const unsigned short* gk = qkv + (size_t)(b * N_SEQ + n0 + srow) * QKVN + C_ + h * E_ + sseg;
  const unsigned short* gv = gk + C_;

  f32x4 acc[4] = {};
  short8 pk0, pk1, pv0, pv1;
  pk0 = *(const short8*)gk;
  pk1 = *(const short8*)(gk + (size_t)32 * QKVN);
  pv0 = *(const short8*)gv;
  pv1 = *(const short8*)(gv + (size_t)32 * QKVN);

  for (int it = 0; it < 8; ++it) {
    {
      s16x4* dk0 = (s16x4*)&ktile[srow][sseg];
      s16x4* dk1 = (s16x4*)&ktile[srow + 32][sseg];
      s16x4* dv0 = (s16x4*)&vtile[srow][sseg];
      s16x4* dv1 = (s16x4*)&vtile[srow + 32][sseg];
      const s16x4* s;
      s = (const s16x4*)&pk0; dk0[0] = s[0]; dk0[1] = s[1];
      s = (const s16x4*)&pk1; dk1[0] = s[0]; dk1[1] = s[1];
      s = (const s16x4*)&pv0; dv0[0] = s[0]; dv0[1] = s[1];
      s = (const s16x4*)&pv1; dv1[0] = s[0]; dv1[1] = s[1];
    }
    __syncthreads();
    if (it < 7) {
      const unsigned short* nk = gk + (size_t)(it + 1) * 64 * QKVN;
      const unsigned short* nv = gv + (size_t)(it + 1) * 64 * QKVN;
      pk0 = *(const short8*)nk;
      pk1 = *(const short8*)(nk + (size_t)32 * QKVN);
      pv0 = *(const short8*)nv;
      pv1 = *(const short8*)(nv + (size_t)32 * QKVN);
    }
#pragma unroll
    for (int ks = 0; ks < 2; ++ks) {
      const int kb = ks * 32;
      short8 av, bk0, bk1, bk2, bk3;
#pragma unroll
      for (int j = 0; j < 8; ++j) {
        const int row = kb + fg * 8 + j;
        av[j]  = (short)vtile[row][w * 16 + fr];
        bk0[j] = (short)ktile[row][fr];
        bk1[j] = (short)ktile[row][16 + fr];
        bk2[j] = (short)ktile[row][32 + fr];
        bk3[j] = (short)ktile[row][48 + fr];
      }
      acc[0] = __builtin_amdgcn_mfma_f32_16x16x32_bf16(av, bk0, acc[0], 0, 0, 0);
      acc[1] = __builtin_amdgcn_mfma_f32_16x16x32_bf16(av, bk1, acc[1], 0, 0, 0);
      acc[2] = __builtin_amdgcn_mfma_f32_16x16x32_bf16(av, bk2, acc[2], 0, 0, 0);
      acc[3] = __builtin_amdgcn_mfma_f32_16x16x32_bf16(av, bk3, acc[3], 0, 0, 0);
    }
    __syncthreads();
  }

  const size_t fbase = (size_t)bh * 64 + w * 16 + fg * 4;
#pragma unroll
  for (int e = 0; e < 4; ++e)
#pragma unroll
    for (int r = 0; r < 4; ++r)
      atomicAdd(&KVT[(fbase + r) * 64 + e * 16 + fr], acc[e][r]);
}

// ---------------------------------------------------------------- attention output (proven)
__global__ __launch_bounds__(256) void attn_out(const unsigned short* __restrict__ qkv,
                                                const float* __restrict__ KVT,
                                                const float* __restrict__ ksum,
                                                unsigned short* __restrict__ hout) {
  const int bid = blockIdx.x;
  const int nc = bid & 63, bh = bid >> 6;
  const int h = bh & 7, b = bh >> 3;
  const int n0 = nc << 6;
  __shared__ float qs[64][68];
  __shared__ float denp[64][4];
  __shared__ float zl[64];
  __shared__ float kss[64];
  const int t = threadIdx.x;

#pragma unroll
  for (int half = 0; half < 2; half++) {
    const int row = (t >> 3) + half * 32;
    const int e0 = (t & 7) * 8;
    const unsigned short* srcq = qkv + (size_t)(b * N_SEQ + n0 + row) * QKVN + h * E_ + e0;
    short8 raw = *(const short8*)srcq;
#pragma unroll
    for (int i = 0; i < 8; i++) qs[row][e0 + i] = bf2f((unsigned short)raw[i]);
  }
  if (t < 64) kss[t] = ksum[bh * 64 + t];
  __syncthreads();

  {
    const int r = t >> 2, qp = t & 3;
    float s = 0.f;
#pragma unroll
    for (int e = 0; e < 16; e++) s = fmaf(qs[r][qp * 16 + e], kss[qp * 16 + e], s);
    denp[r][qp] = s;
  }
  __syncthreads();
  if (t < 64) zl[t] = 1.0f / (denp[t][0] + denp[t][1] + denp[t][2] + denp[t][3] + 1e-6f);
  __syncthreads();

  const int f = t & 63, rg = t >> 6;
  float kvc[64];
  const float* kvp = KVT + (size_t)bh * 4096 + (size_t)f * 64;
#pragma unroll
  for (int i = 0; i < 16; i++) {
    float4 v4 = *(const float4*)(kvp + i * 4);
    kvc[4 * i] = v4.x; kvc[4 * i + 1] = v4.y; kvc[4 * i + 2] = v4.z; kvc[4 * i + 3] = v4.w;
  }
#pragma unroll
  for (int i = 0; i < 16; i++) {
    const int row = rg * 16 + i;
    float a = 0.f;
#pragma unroll
    for (int e4 = 0; e4 < 16; e4++) {
      float4 qv = *(const float4*)&qs[row][e4 * 4];
      a = fmaf(qv.x, kvc[4 * e4 + 0], a);
      a = fmaf(qv.y, kvc[4 * e4 + 1], a);
      a = fmaf(qv.z, kvc[4 * e4 + 2], a);
      a = fmaf(qv.w, kvc[4 * e4 + 3], a);
    }
    const float val = a * zl[row];
    hout[(size_t)(b * N_SEQ + n0 + row) * C_ + h * E_ + f] = f2bf(val);
  }
}

// ---------------------------------------------------------------- launcher
extern "C" void kernel_launch(void* const* d_in, const int* in_sizes, int n_in,
                              void* d_out, int out_size, void* d_ws, size_t ws_size,
                              hipStream_t stream) {
  const float* x  = (const float*)d_in[0];
  const float* wq = (const float*)d_in[1];
  const float* wp = (const float*)d_in[2];
  const float* bp = (const float*)d_in[3];
  float* out = (float*)d_out;

  char* ws = (char*)d_ws;
  const size_t SZ_XBF  = (size_t)M_TOT * C_ * 2;      //  67108864
  const size_t SZ_QKV  = (size_t)M_TOT * QKVN * 2;    // 201326592
  const size_t SZ_WQ   = (size_t)QKVN * C_ * 2;       //   1572864
  const size_t SZ_WP   = (size_t)C_ * C_ * 2;         //    524288
  const size_t SZ_KVT  = (size_t)128 * 64 * 64 * 4;   //   2097152
  unsigned short* x_bf   = (unsigned short*)(ws);
  unsigned short* qkv_bf = (unsigned short*)(ws + SZ_XBF);
  unsigned short* wq_bf  = (unsigned short*)(ws + SZ_XBF + SZ_QKV);
  unsigned short* wp_bf  = (unsigned short*)(ws + SZ_XBF + SZ_QKV + SZ_WQ);
  float* KVT   = (float*)(ws + SZ_XBF + SZ_QKV + SZ_WQ + SZ_WP);
  float* ksumb = (float*)(ws + SZ_XBF + SZ_QKV + SZ_WQ + SZ_WP + SZ_KVT);
  unsigned short* hout = x_bf;  // reuse: x_bf dead after GEMM1

  cvt_all<<<17416, 256, 0, stream>>>(x, wq, wp, x_bf, wq_bf, wp_bf, KVT);

  gemm_bt<1><<<512 * 12, 256, 0, stream>>>(x_bf, wq_bf, qkv_bf, nullptr, ksumb,
                                           M_TOT, QKVN, 12);
  kv_mfma<<<1024, 256, 0, stream>>>(qkv_bf, KVT);
  attn_out<<<8192, 256, 0, stream>>>(qkv_bf, KVT, ksumb, hout);
  gemm_bt<2><<<512 * 4, 256, 0, stream>>>(hout, wp_bf, out, bp, nullptr,
                                          M_TOT, C_, 4);
}

// Round 15
// 357.132 us; speedup vs baseline: 1.0417x; 1.0417x over previous
//
#include <hip/hip_runtime.h>
#include <stdint.h>
#include <stddef.h>

// Problem constants
#define B_    16
#define N_SEQ 4096
#define C_    512
#define H_    8
#define E_    64
#define M_TOT (B_ * N_SEQ)   // 65536
#define QKVN  (3 * C_)       // 1536

typedef __attribute__((ext_vector_type(8))) short short8;
typedef __attribute__((ext_vector_type(4))) short s16x4;
typedef __attribute__((ext_vector_type(4))) float f32x4;

__device__ __forceinline__ unsigned short f2bf(float f) {
  uint32_t u = __builtin_bit_cast(uint32_t, f);
  return (unsigned short)((u + 0x7fffu + ((u >> 16) & 1u)) >> 16);  // RNE
}
__device__ __forceinline__ float bf2f(unsigned short h) {
  uint32_t u = ((uint32_t)h) << 16;
  return __builtin_bit_cast(float, u);
}

// ---------------------------------------------------------------- cvt + zero (one dispatch)
__global__ __launch_bounds__(256) void cvt_all(const float* __restrict__ x,
                                               const float* __restrict__ wq,
                                               const float* __restrict__ wp,
                                               unsigned short* __restrict__ xo,
                                               unsigned short* __restrict__ wqo,
                                               unsigned short* __restrict__ wpo,
                                               float* __restrict__ zbuf) {
  const int bb = blockIdx.x;
  if (bb >= 16896) {
    size_t i = ((size_t)(bb - 16896) * 256 + threadIdx.x) * 4;
    *(float4*)(zbuf + i) = make_float4(0.f, 0.f, 0.f, 0.f);
    return;
  }
  const float* in;
  unsigned short* out;
  size_t base;
  if (bb < 16384)      { in = x;  out = xo;  base = (size_t)bb * 2048; }
  else if (bb < 16768) { in = wq; out = wqo; base = (size_t)(bb - 16384) * 2048; }
  else                 { in = wp; out = wpo; base = (size_t)(bb - 16768) * 2048; }
  size_t i = base + (size_t)threadIdx.x * 8;
  float4 a = *(const float4*)(in + i);
  float4 b = *(const float4*)(in + i + 4);
  short8 o;
  o[0] = (short)f2bf(a.x); o[1] = (short)f2bf(a.y);
  o[2] = (short)f2bf(a.z); o[3] = (short)f2bf(a.w);
  o[4] = (short)f2bf(b.x); o[5] = (short)f2bf(b.y);
  o[6] = (short)f2bf(b.z); o[7] = (short)f2bf(b.w);
  *(short8*)(out + i) = o;
}

#define GLD16(g, l)                                                              \
  __builtin_amdgcn_global_load_lds(                                              \
      (const __attribute__((address_space(1))) void*)(g),                        \
      (__attribute__((address_space(3))) void*)(l), 16, 0, 0)

// ---------------------------------------------------------------- GEMM (C = A * B^T), bf16 in, f32 accum
// Tile 128x128, BK=64, 4 waves (2M x 2N, wave-tile 64x64, acc = 64 AGPR),
// double-buffered LDS = 64 KiB -> TWO independent blocks/CU (128 KiB <= 160;
// regs ~140 <= 256 at 2 waves/SIMD). One block's prologue/epilogue/barrier
// stalls overlap the other's K-loop — R12's monolithic 128-KiB block could not.
// Keeps R12's verified pieces: BK=64 (8 K-tiles, 32 MFMA/barrier/wave),
// T2 slot-XOR swizzle (SQ_LDS_BANK_CONFLICT = 0 measured), 2-phase schedule
// {STAGE(kt+1) -> swizzled ds_read -> setprio(1) MFMA setprio(0) -> barrier},
// XCD-aware bijective block swizzle.
// MODE 1: qkv epilogue -> bf16, relu+0.125 on cols < 1024; ksum for k cols
// MODE 2: f32 + bias
template <int MODE>
__global__ __launch_bounds__(256, 2) void gemm_bt(
    const unsigned short* __restrict__ A, const unsigned short* __restrict__ Bm,
    void* __restrict__ Cout, const float* __restrict__ bias,
    float* __restrict__ ksum, int M, int N, int NT) {
  const int K = 512;
  __shared__ unsigned short lds[2][2][128 * 64];  // [dbuf][A|B][128 rows x 64 k] = 64 KiB
  // XCD-aware bijective swizzle (grid % 8 == 0)
  const int q8 = gridDim.x >> 3;
  int bid = blockIdx.x;
  bid = (bid & 7) * q8 + (bid >> 3);
  const int mt = bid / NT, nt = bid - mt * NT;
  const int row0 = mt << 7, col0 = nt << 7;
  const int tid = threadIdx.x;
  const int lane = tid & 63, wave = tid >> 6;
  const int wm = wave & 1, wn = wave >> 1;   // wave tile: rows wm*64, cols wn*64
  const int fr = lane & 15, fg = lane >> 4;

  // staging: thread t covers LDS position q = i*256 + t (16B units);
  // row = q>>3, slot' = q&7 holds global slot (q&7)^(row&7)  [R8-verified]
  const int s_row = tid >> 3;                   // 0..31 (+32 per issue)
  const int s_slot = (tid & 7) ^ (s_row & 7);   // pre-swizzled global slot
  const unsigned short* gA = A + (size_t)(row0 + s_row) * K + s_slot * 8;
  const unsigned short* gB = Bm + (size_t)(col0 + s_row) * K + s_slot * 8;

  f32x4 acc[4][4] = {};

#define STAGE(kt)                                                        \
  {                                                                      \
    unsigned short* dA = &lds[(kt) & 1][0][tid * 8];                     \
    unsigned short* dB = &lds[(kt) & 1][1][tid * 8];                     \
    _Pragma("unroll")                                                    \
    for (int i = 0; i < 4; i++) {                                        \
      GLD16(gA + (size_t)i * 32 * K + (kt) * 64, dA + i * 2048);         \
      GLD16(gB + (size_t)i * 32 * K + (kt) * 64, dB + i * 2048);         \
    }                                                                    \
  }

  STAGE(0);
  __syncthreads();

  for (int kt = 0; kt < 8; ++kt) {
    if (kt < 7) STAGE(kt + 1);
    const unsigned short* bufA = &lds[kt & 1][0][0];
    const unsigned short* bufB = &lds[kt & 1][1][0];
#pragma unroll
    for (int kk = 0; kk < 2; ++kk) {
      const int sl = ((kk * 4 + fg) ^ (fr & 7)) * 8;
      short8 af[4], bg[4];
#pragma unroll
      for (int m = 0; m < 4; m++)
        af[m] = *(const short8*)&bufA[(wm * 64 + m * 16 + fr) * 64 + sl];
#pragma unroll
      for (int n = 0; n < 4; n++)
        bg[n] = *(const short8*)&bufB[(wn * 64 + n * 16 + fr) * 64 + sl];
      __builtin_amdgcn_s_setprio(1);
#pragma unroll
      for (int m = 0; m < 4; m++)
#pragma unroll
        for (int n = 0; n < 4; n++)
          acc[m][n] = __builtin_amdgcn_mfma_f32_16x16x32_bf16(af[m], bg[n], acc[m][n], 0, 0, 0);
      __builtin_amdgcn_s_setprio(0);
    }
    __syncthreads();   // stage(kt+1) landed (vmcnt drained) + readers joined
  }
#undef STAGE

  if (MODE == 1) {
    unsigned short* Cq = (unsigned short*)Cout;
    const int cw0 = col0 + wn * 64;
    const bool isqk = (cw0 < 2 * C_);
    const bool isk = (cw0 >= C_) && (cw0 < 2 * C_);
    float ksp[4] = {0.f, 0.f, 0.f, 0.f};
#pragma unroll
    for (int m = 0; m < 4; m++) {
      const int r0 = row0 + wm * 64 + m * 16 + fg * 4;
#pragma unroll
      for (int n = 0; n < 4; n++) {
        const int c = cw0 + n * 16 + fr;
#pragma unroll
        for (int r = 0; r < 4; r++) {
          float v = acc[m][n][r];
          if (isqk) v = fmaxf(v, 0.0f) + 0.125f;   // relu + E^-0.5
          if (isk) ksp[n] += v;
          Cq[(size_t)(r0 + r) * N + c] = f2bf(v);
        }
      }
    }
    if (isk) {
      const int b = row0 >> 12;
#pragma unroll
      for (int n = 0; n < 4; n++) {
        float s = ksp[n];
        s += __shfl_xor(s, 16, 64);
        s += __shfl_xor(s, 32, 64);
        if (lane < 16) {
          const int cc = cw0 + n * 16 + lane - C_;  // 0..511
          atomicAdd(&ksum[(size_t)((b << 3) + (cc >> 6)) * 64 + (cc & 63)], s);
        }
      }
    }
  } else {
    float* Cf = (float*)Cout;
#pragma unroll
    for (int m = 0; m < 4; m++) {
      const int r0 = row0 + wm * 64 + m * 16 + fg * 4;
#pragma unroll
      for (int n = 0; n < 4; n++) {
        const int c = col0 + wn * 64 + n * 16 + fr;
        const float bb = bias[c];
#pragma unroll
        for (int r = 0; r < 4; r++)
          Cf[(size_t)(r0 + r) * N + c] = acc[m][n][r] + bb;
      }
    }
  }
}

// ---------------------------------------------------------------- KV^T via MFMA (proven)
__global__ __launch_bounds__(256) void kv_mfma(const unsigned short* __restrict__ qkv,
                                               float* __restrict__ KVT) {
  const int bid = blockIdx.x;
  const int ch = bid & 7, bh = bid >> 3;
  const int h = bh & 7, b = bh >> 3;
  const int n0 = ch << 9;
  __shared__ unsigned short ktile[64][68];
  __shared__ unsigned short vtile[64][68];
  const int tid = threadIdx.x;
  const int lane = tid & 63, w = tid >> 6;
  const int fr = lane & 15, fg = lane >> 4;
  const int srow = tid >> 3;
  const int sseg = (tid & 7) << 3;
  const unsigned short* gk = qkv + (size_t)(b * N_SEQ + n0 + srow) * QKVN + C_ + h * E_ + sseg;
  const unsigned short* gv = gk + C_;

  f32x4 acc[4] = {};
  short8 pk0, pk1, pv0, pv1;
  pk0 = *(const short8*)gk;
  pk1 = *(const short8*)(gk + (size_t)32 * QKVN);
  pv0 = *(const short8*)gv;
  pv1 = *(const short8*)(gv + (size_t)32 * QKVN);

  for (int it = 0; it < 8; ++it) {
    {
      s16x4* dk0 = (s16x4*)&ktile[srow][sseg];
      s16x4* dk1 = (s16x4*)&ktile[srow + 32][sseg];
      s16x4* dv0 = (s16x4*)&vtile[srow][sseg];
      s16x4* dv1 = (s16x4*)&vtile[srow + 32][sseg];
      const s16x4* s;
      s = (const s16x4*)&pk0; dk0[0] = s[0]; dk0[1] = s[1];
      s = (const s16x4*)&pk1; dk1[0] = s[0]; dk1[1] = s[1];
      s = (const s16x4*)&pv0; dv0[0] = s[0]; dv0[1] = s[1];
      s = (const s16x4*)&pv1; dv1[0] = s[0]; dv1[1] = s[1];
    }
    __syncthreads();
    if (it < 7) {
      const unsigned short* nk = gk + (size_t)(it + 1) * 64 * QKVN;
      const unsigned short* nv = gv + (size_t)(it + 1) * 64 * QKVN;
      pk0 = *(const short8*)nk;
      pk1 = *(const short8*)(nk + (size_t)32 * QKVN);
      pv0 = *(const short8*)nv;
      pv1 = *(const short8*)(nv + (size_t)32 * QKVN);
    }
#pragma unroll
    for (int ks = 0; ks < 2; ++ks) {
      const int kb = ks * 32;
      short8 av, bk0, bk1, bk2, bk3;
#pragma unroll
      for (int j = 0; j < 8; ++j) {
        const int row = kb + fg * 8 + j;
        av[j]  = (short)vtile[row][w * 16 + fr];
        bk0[j] = (short)ktile[row][fr];
        bk1[j] = (short)ktile[row][16 + fr];
        bk2[j] = (short)ktile[row][32 + fr];
        bk3[j] = (short)ktile[row][48 + fr];
      }
      acc[0] = __builtin_amdgcn_mfma_f32_16x16x32_bf16(av, bk0, acc[0], 0, 0, 0);
      acc[1] = __builtin_amdgcn_mfma_f32_16x16x32_bf16(av, bk1, acc[1], 0, 0, 0);
      acc[2] = __builtin_amdgcn_mfma_f32_16x16x32_bf16(av, bk2, acc[2], 0, 0, 0);
      acc[3] = __builtin_amdgcn_mfma_f32_16x16x32_bf16(av, bk3, acc[3], 0, 0, 0);
    }
    __syncthreads();
  }

  const size_t fbase = (size_t)bh * 64 + w * 16 + fg * 4;
#pragma unroll
  for (int e = 0; e < 4; ++e)
#pragma unroll
    for (int r = 0; r < 4; ++r)
      atomicAdd(&KVT[(fbase + r) * 64 + e * 16 + fr], acc[e][r]);
}

// ---------------------------------------------------------------- attention output (proven)
__global__ __launch_bounds__(256) void attn_out(const unsigned short* __restrict__ qkv,
                                                const float* __restrict__ KVT,
                                                const float* __restrict__ ksum,
                                                unsigned short* __restrict__ hout) {
  const int bid = blockIdx.x;
  const int nc = bid & 63, bh = bid >> 6;
  const int h = bh & 7, b = bh >> 3;
  const int n0 = nc << 6;
  __shared__ float qs[64][68];
  __shared__ float denp[64][4];
  __shared__ float zl[64];
  __shared__ float kss[64];
  const int t = threadIdx.x;

#pragma unroll
  for (int half = 0; half < 2; half++) {
    const int row = (t >> 3) + half * 32;
    const int e0 = (t & 7) * 8;
    const unsigned short* srcq = qkv + (size_t)(b * N_SEQ + n0 + row) * QKVN + h * E_ + e0;
    short8 raw = *(const short8*)srcq;
#pragma unroll
    for (int i = 0; i < 8; i++) qs[row][e0 + i] = bf2f((unsigned short)raw[i]);
  }
  if (t < 64) kss[t] = ksum[bh * 64 + t];
  __syncthreads();

  {
    const int r = t >> 2, qp = t & 3;
    float s = 0.f;
#pragma unroll
    for (int e = 0; e < 16; e++) s = fmaf(qs[r][qp * 16 + e], kss[qp * 16 + e], s);
    denp[r][qp] = s;
  }
  __syncthreads();
  if (t < 64) zl[t] = 1.0f / (denp[t][0] + denp[t][1] + denp[t][2] + denp[t][3] + 1e-6f);
  __syncthreads();

  const int f = t & 63, rg = t >> 6;
  float kvc[64];
  const float* kvp = KVT + (size_t)bh * 4096 + (size_t)f * 64;
#pragma unroll
  for (int i = 0; i < 16; i++) {
    float4 v4 = *(const float4*)(kvp + i * 4);
    kvc[4 * i] = v4.x; kvc[4 * i + 1] = v4.y; kvc[4 * i + 2] = v4.z; kvc[4 * i + 3] = v4.w;
  }
#pragma unroll
  for (int i = 0; i < 16; i++) {
    const int row = rg * 16 + i;
    float a = 0.f;
#pragma unroll
    for (int e4 = 0; e4 < 16; e4++) {
      float4 qv = *(const float4*)&qs[row][e4 * 4];
      a = fmaf(qv.x, kvc[4 * e4 + 0], a);
      a = fmaf(qv.y, kvc[4 * e4 + 1], a);
      a = fmaf(qv.z, kvc[4 * e4 + 2], a);
      a = fmaf(qv.w, kvc[4 * e4 + 3], a);
    }
    const float val = a * zl[row];
    hout[(size_t)(b * N_SEQ + n0 + row) * C_ + h * E_ + f] = f2bf(val);
  }
}

// ---------------------------------------------------------------- launcher
extern "C" void kernel_launch(void* const* d_in, const int* in_sizes, int n_in,
                              void* d_out, int out_size, void* d_ws, size_t ws_size,
                              hipStream_t stream) {
  const float* x  = (const float*)d_in[0];
  const float* wq = (const float*)d_in[1];
  const float* wp = (const float*)d_in[2];
  const float* bp = (const float*)d_in[3];
  float* out = (float*)d_out;

  char* ws = (char*)d_ws;
  const size_t SZ_XBF  = (size_t)M_TOT * C_ * 2;      //  67108864
  const size_t SZ_QKV  = (size_t)M_TOT * QKVN * 2;    // 201326592
  const size_t SZ_WQ   = (size_t)QKVN * C_ * 2;       //   1572864
  const size_t SZ_WP   = (size_t)C_ * C_ * 2;         //    524288
  const size_t SZ_KVT  = (size_t)128 * 64 * 64 * 4;   //   2097152
  unsigned short* x_bf   = (unsigned short*)(ws);
  unsigned short* qkv_bf = (unsigned short*)(ws + SZ_XBF);
  unsigned short* wq_bf  = (unsigned short*)(ws + SZ_XBF + SZ_QKV);
  unsigned short* wp_bf  = (unsigned short*)(ws + SZ_XBF + SZ_QKV + SZ_WQ);
  float* KVT   = (float*)(ws + SZ_XBF + SZ_QKV + SZ_WQ + SZ_WP);
  float* ksumb = (float*)(ws + SZ_XBF + SZ_QKV + SZ_WQ + SZ_WP + SZ_KVT);
  unsigned short* hout = x_bf;  // reuse: x_bf dead after GEMM1

  cvt_all<<<17416, 256, 0, stream>>>(x, wq, wp, x_bf, wq_bf, wp_bf, KVT);

  gemm_bt<1><<<6144, 256, 0, stream>>>(x_bf, wq_bf, qkv_bf, nullptr, ksumb,
                                       M_TOT, QKVN, 12);
  kv_mfma<<<1024, 256, 0, stream>>>(qkv_bf, KVT);
  attn_out<<<8192, 256, 0, stream>>>(qkv_bf, KVT, ksumb, hout);
  gemm_bt<2><<<2048, 256, 0, stream>>>(hout, wp_bf, out, bp, nullptr,
                                       M_TOT, C_, 4);
}